// Round 4
// baseline (361.784 us; speedup 1.0000x reference)
//
#include <hip/hip_runtime.h>
#include <math.h>

#define B_   32
#define N_   128
#define H_   100
#define VT   4            // v rows per msgpart block
#define WS   4            // w-split chunks
#define WCH  (N_ / WS)    // 32 w per chunk
#define ROWS (B_ * N_)    // 4096
#define RH   (ROWS * H_)  // 409600

// ---------------------------------------------------------------------------
// K0: maskf[row*N+w] = (sum_e edges[row,w,:] != 0) as float; nmask[row].
__global__ __launch_bounds__(256) void k_mask(const float* __restrict__ edges,
                                              float* __restrict__ maskf,
                                              float* __restrict__ nmask) {
    const int t = threadIdx.x, lane = t & 63, wv = t >> 6;
    const int row = blockIdx.x * 4 + wv;
    const float4* eg = (const float4*)(edges + (size_t)row * N_ * 4);
    const float4 e0 = eg[lane], e1 = eg[lane + 64];
    const float s0 = (e0.x + e0.y) + (e0.z + e0.w);
    const float s1 = (e1.x + e1.y) + (e1.z + e1.w);
    maskf[row * N_ + lane]      = (s0 != 0.f) ? 1.f : 0.f;
    maskf[row * N_ + 64 + lane] = (s1 != 0.f) ? 1.f : 0.f;
    const unsigned long long bl = __ballot((s0 != 0.f) || (s1 != 0.f));
    if (lane == 0) nmask[row] = bl ? 1.f : 0.f;
}

// ---------------------------------------------------------------------------
// K1: initial hv = nodes@Wv, hw = nodes@Ww. 2 rows per 128-thread block.
__global__ __launch_bounds__(128) void k_proj0(const float* __restrict__ nodes,
                                               const float* __restrict__ Wv,
                                               const float* __restrict__ Ww,
                                               float* __restrict__ hv,
                                               float* __restrict__ hw) {
    __shared__ float nod_s[2 * H_];
    const int row0 = blockIdx.x * 2;
    const int t = threadIdx.x, r = t >> 6, j = t & 63;
    const bool act = j < 50;
    const int row = row0 + r;
    const float4* ng = (const float4*)(nodes + (size_t)row0 * H_);
    for (int idx = t; idx < 50; idx += 128) ((float4*)nod_s)[idx] = ng[idx];
    __syncthreads();
    if (!act) return;
    const float2* Wv2 = (const float2*)Wv;
    const float2* Ww2 = (const float2*)Ww;
    float va0 = 0, va1 = 0, wa0 = 0, wa1 = 0;
    const float* hr = nod_s + r * H_;
#pragma unroll 4
    for (int k = 0; k < H_; ++k) {
        const float hk = hr[k];
        const float2 wv = Wv2[k * 50 + j];
        const float2 ww = Ww2[k * 50 + j];
        va0 = fmaf(hk, wv.x, va0); va1 = fmaf(hk, wv.y, va1);
        wa0 = fmaf(hk, ww.x, wa0); wa1 = fmaf(hk, ww.y, wa1);
    }
    *(float2*)(hv + (size_t)row * H_ + 2 * j) = make_float2(va0, va1);
    *(float2*)(hw + (size_t)row * H_ + 2 * j) = make_float2(wa0, wa1);
}

// ---------------------------------------------------------------------------
// K2: partial messages. Block = (b, v-tile of 4, w-chunk of 32), 128 threads,
// thread = (v, h-quad). No LDS, no barriers; 4096 blocks (16/CU co-resident).
// msgpart[wc][row][h] += relu terms over the block's 32 w.
__global__ __launch_bounds__(128, 8) void k_msgpart(const float* __restrict__ edges,
                                                    const float* __restrict__ maskf,
                                                    const float* __restrict__ hv,
                                                    const float* __restrict__ hw,
                                                    const float* __restrict__ We,
                                                    float* __restrict__ msgpart) {
    const int b = blockIdx.y;
    const int vt = blockIdx.x >> 2, wc = blockIdx.x & 3;
    const int t = threadIdx.x;
    const int v = t / 25, hq = t % 25;
    if (v >= VT) return;
    const int row = b * N_ + vt * VT + v;
    const int w0 = wc * WCH;

    const float4 hv4 = *(const float4*)(hv + (size_t)row * H_ + hq * 4);
    const float4 we0 = *(const float4*)(We + 0 * H_ + hq * 4);
    const float4 we1 = *(const float4*)(We + 1 * H_ + hq * 4);
    const float4 we2 = *(const float4*)(We + 2 * H_ + hq * 4);
    const float4 we3 = *(const float4*)(We + 3 * H_ + hq * 4);

    const float4* ep  = (const float4*)(edges + ((size_t)row * N_ + w0) * 4);
    const float*  mp  = maskf + row * N_ + w0;
    const float*  hwp = hw + ((size_t)b * N_ + w0) * H_ + hq * 4;

    float4 acc = make_float4(0.f, 0.f, 0.f, 0.f);
#pragma unroll 4
    for (int w = 0; w < WCH; ++w) {
        const float4 e  = ep[w];
        const float  m  = mp[w];
        const float4 h4 = *(const float4*)(hwp + w * H_);
        float p0 = hv4.x + h4.x, p1 = hv4.y + h4.y;
        float p2 = hv4.z + h4.z, p3 = hv4.w + h4.w;
        p0 = fmaf(e.x, we0.x, p0); p1 = fmaf(e.x, we0.y, p1);
        p2 = fmaf(e.x, we0.z, p2); p3 = fmaf(e.x, we0.w, p3);
        p0 = fmaf(e.y, we1.x, p0); p1 = fmaf(e.y, we1.y, p1);
        p2 = fmaf(e.y, we1.z, p2); p3 = fmaf(e.y, we1.w, p3);
        p0 = fmaf(e.z, we2.x, p0); p1 = fmaf(e.z, we2.y, p1);
        p2 = fmaf(e.z, we2.z, p2); p3 = fmaf(e.z, we2.w, p3);
        p0 = fmaf(e.w, we3.x, p0); p1 = fmaf(e.w, we3.y, p1);
        p2 = fmaf(e.w, we3.z, p2); p3 = fmaf(e.w, we3.w, p3);
        acc.x = fmaf(m, fmaxf(p0, 0.f), acc.x);
        acc.y = fmaf(m, fmaxf(p1, 0.f), acc.y);
        acc.z = fmaf(m, fmaxf(p2, 0.f), acc.z);
        acc.w = fmaf(m, fmaxf(p3, 0.f), acc.w);
    }
    *(float4*)(msgpart + ((size_t)wc * ROWS + row) * H_ + hq * 4) = acc;
}

// ---------------------------------------------------------------------------
// K3: row-local: msg = sum of 4 partials; u = [hid,msg]@Wu; hidden = tanh/keep;
// optionally next pass's hv/hw projections. 2 rows per 128-thread block.
__global__ __launch_bounds__(128) void k_update(const float* __restrict__ hid_in,
                                                const float* __restrict__ msgpart,
                                                const float* __restrict__ Wu,
                                                const float* __restrict__ Wv,
                                                const float* __restrict__ Ww,
                                                const float* __restrict__ nmask,
                                                float* __restrict__ hidden,
                                                float* __restrict__ hv,
                                                float* __restrict__ hw,
                                                int do_proj) {
    __shared__ float hid_s[2 * H_], msg_s[2 * H_], hn_s[2 * H_];
    const int row0 = blockIdx.x * 2;
    const int t = threadIdx.x, r = t >> 6, j = t & 63;
    const bool act = j < 50;
    const int row = row0 + r;
    {
        const float4* hg = (const float4*)(hid_in + (size_t)row0 * H_);
        const float4* m0 = (const float4*)(msgpart + (size_t)row0 * H_);
        for (int idx = t; idx < 50; idx += 128) {
            ((float4*)hid_s)[idx] = hg[idx];
            float4 a = m0[idx];
            const float4 c = m0[idx + RH / 4];
            const float4 d = m0[idx + 2 * (RH / 4)];
            const float4 e = m0[idx + 3 * (RH / 4)];
            a.x += c.x + d.x + e.x; a.y += c.y + d.y + e.y;
            a.z += c.z + d.z + e.z; a.w += c.w + d.w + e.w;
            ((float4*)msg_s)[idx] = a;
        }
    }
    __syncthreads();
    if (act) {
        const float2* Wu2 = (const float2*)Wu;
        float u0 = 0.f, u1 = 0.f;
        const float* hr = hid_s + r * H_;
        const float* mr = msg_s + r * H_;
#pragma unroll 4
        for (int k = 0; k < H_; ++k) {
            const float hk = hr[k];
            const float2 wu = Wu2[k * 50 + j];
            u0 = fmaf(hk, wu.x, u0); u1 = fmaf(hk, wu.y, u1);
        }
#pragma unroll 4
        for (int k = 0; k < H_; ++k) {
            const float mk = mr[k];
            const float2 wu = Wu2[(H_ + k) * 50 + j];
            u0 = fmaf(mk, wu.x, u0); u1 = fmaf(mk, wu.y, u1);
        }
        const float nm = nmask[row];
        float2 nh;
        nh.x = (nm != 0.f) ? tanhf(u0) : hr[2 * j];
        nh.y = (nm != 0.f) ? tanhf(u1) : hr[2 * j + 1];
        *(float2*)(hidden + (size_t)row * H_ + 2 * j) = nh;
        if (do_proj) *(float2*)(hn_s + r * H_ + 2 * j) = nh;
    }
    if (do_proj) {
        __syncthreads();
        if (act) {
            const float2* Wv2 = (const float2*)Wv;
            const float2* Ww2 = (const float2*)Ww;
            float va0 = 0, va1 = 0, wa0 = 0, wa1 = 0;
            const float* hr = hn_s + r * H_;
#pragma unroll 4
            for (int k = 0; k < H_; ++k) {
                const float hk = hr[k];
                const float2 wv = Wv2[k * 50 + j];
                const float2 ww = Ww2[k * 50 + j];
                va0 = fmaf(hk, wv.x, va0); va1 = fmaf(hk, wv.y, va1);
                wa0 = fmaf(hk, ww.x, wa0); wa1 = fmaf(hk, ww.y, wa1);
            }
            *(float2*)(hv + (size_t)row * H_ + 2 * j) = make_float2(va0, va1);
            *(float2*)(hw + (size_t)row * H_ + 2 * j) = make_float2(wa0, wa1);
        }
    }
}

// ---------------------------------------------------------------------------
// K4: readout. 2 rows/block; block-reduce then one atomic per (b,h) pair-row.
__global__ __launch_bounds__(128) void k_readout(const float* __restrict__ hidden,
                                                 const float* __restrict__ nodes,
                                                 const float* __restrict__ Wr,
                                                 const float* __restrict__ nmask,
                                                 float* __restrict__ out) {
    __shared__ float hid_s[2 * H_], nod_s[2 * H_], red_s[2 * H_];
    const int row0 = blockIdx.x * 2, b = row0 >> 7;
    const int t = threadIdx.x, r = t >> 6, j = t & 63;
    const bool act = j < 50;
    const int row = row0 + r;
    {
        const float4* hg = (const float4*)(hidden + (size_t)row0 * H_);
        const float4* ng = (const float4*)(nodes + (size_t)row0 * H_);
        for (int idx = t; idx < 50; idx += 128) {
            ((float4*)hid_s)[idx] = hg[idx];
            ((float4*)nod_s)[idx] = ng[idx];
        }
    }
    __syncthreads();
    if (act) {
        const float2* Wr2 = (const float2*)Wr;
        float u0 = 0.f, u1 = 0.f;
        const float* hr = hid_s + r * H_;
        const float* nr = nod_s + r * H_;
#pragma unroll 4
        for (int k = 0; k < H_; ++k) {
            const float hk = hr[k];
            const float2 wr = Wr2[k * 50 + j];
            u0 = fmaf(hk, wr.x, u0); u1 = fmaf(hk, wr.y, u1);
        }
#pragma unroll 4
        for (int k = 0; k < H_; ++k) {
            const float nk = nr[k];
            const float2 wr = Wr2[(H_ + k) * 50 + j];
            u0 = fmaf(nk, wr.x, u0); u1 = fmaf(nk, wr.y, u1);
        }
        const float nm = nmask[row];
        red_s[r * H_ + 2 * j]     = nm * fmaxf(u0, 0.f);
        red_s[r * H_ + 2 * j + 1] = nm * fmaxf(u1, 0.f);
    }
    __syncthreads();
    if (t < H_) atomicAdd(out + b * H_ + t, red_s[t] + red_s[H_ + t]);
}

// ---------------------------------------------------------------------------
extern "C" void kernel_launch(void* const* d_in, const int* in_sizes, int n_in,
                              void* d_out, int out_size, void* d_ws, size_t ws_size,
                              hipStream_t stream) {
    const float* nodes = (const float*)d_in[0];
    const float* edges = (const float*)d_in[1];
    const float* Wv    = (const float*)d_in[2];
    const float* Ww    = (const float*)d_in[3];
    const float* We    = (const float*)d_in[4];
    const float* Wu    = (const float*)d_in[5];
    const float* Wr    = (const float*)d_in[6];
    float* out = (float*)d_out;

    float* hidden  = (float*)d_ws;            // RH
    float* hv      = hidden + RH;             // RH
    float* hw      = hv + RH;                 // RH (single buffer: kernel-serialized)
    float* nmask   = hw + RH;                 // ROWS
    float* maskf   = nmask + ROWS;            // ROWS*N_
    float* msgpart = maskf + (size_t)ROWS * N_;  // WS*RH

    hipMemsetAsync(d_out, 0, (size_t)out_size * sizeof(float), stream);

    k_mask<<<ROWS / 4, 256, 0, stream>>>(edges, maskf, nmask);
    k_proj0<<<ROWS / 2, 128, 0, stream>>>(nodes, Wv, Ww, hv, hw);

    const dim3 mgrid((N_ / VT) * WS, B_);     // (128, 32) = 4096 blocks
    // pass 0: pre-update hidden = nodes
    k_msgpart<<<mgrid, 128, 0, stream>>>(edges, maskf, hv, hw, We, msgpart);
    k_update<<<ROWS / 2, 128, 0, stream>>>(nodes, msgpart, Wu, Wv, Ww, nmask,
                                           hidden, hv, hw, 1);
    k_msgpart<<<mgrid, 128, 0, stream>>>(edges, maskf, hv, hw, We, msgpart);
    k_update<<<ROWS / 2, 128, 0, stream>>>(hidden, msgpart, Wu, Wv, Ww, nmask,
                                           hidden, hv, hw, 1);
    k_msgpart<<<mgrid, 128, 0, stream>>>(edges, maskf, hv, hw, We, msgpart);
    k_update<<<ROWS / 2, 128, 0, stream>>>(hidden, msgpart, Wu, Wv, Ww, nmask,
                                           hidden, hv, hw, 0);

    k_readout<<<ROWS / 2, 128, 0, stream>>>(hidden, nodes, Wr, nmask, out);
}

// Round 5
// 212.299 us; speedup vs baseline: 1.7041x; 1.7041x over previous
//
#include <hip/hip_runtime.h>
#include <math.h>

#define B_   32
#define N_   128
#define H_   100
#define ROWS (B_ * N_)    // 4096
#define RH   (ROWS * H_)  // 409600

// ---------------------------------------------------------------------------
// K0: nmask[row] = any(edge-sum != 0) over w. One wave per row.
__global__ __launch_bounds__(256) void k_mask(const float* __restrict__ edges,
                                              float* __restrict__ nmask) {
    const int t = threadIdx.x, lane = t & 63, wv = t >> 6;
    const int row = blockIdx.x * 4 + wv;
    const float4* eg = (const float4*)(edges + (size_t)row * N_ * 4);
    const float4 e0 = eg[lane], e1 = eg[lane + 64];
    const float s0 = (e0.x + e0.y) + (e0.z + e0.w);
    const float s1 = (e1.x + e1.y) + (e1.z + e1.w);
    const unsigned long long bl = __ballot((s0 != 0.f) || (s1 != 0.f));
    if (lane == 0) nmask[row] = bl ? 1.f : 0.f;
}

// ---------------------------------------------------------------------------
// K1: hv = nodes@Wv, hw = nodes@Ww. 2 rows per 256-thread block; lane j = h.
__global__ __launch_bounds__(256, 6) void k_proj0(const float* __restrict__ nodes,
                                                  const float* __restrict__ Wv,
                                                  const float* __restrict__ Ww,
                                                  float* __restrict__ hv,
                                                  float* __restrict__ hw) {
    __shared__ float nod_s[2][H_];
    const int row0 = blockIdx.x * 2;
    const int t = threadIdx.x, r = t >> 7, j = t & 127;
    {
        const float4* ng = (const float4*)(nodes + (size_t)row0 * H_);
        if (t < 50) ((float4*)nod_s)[t] = ng[t];
    }
    __syncthreads();
    if (j >= H_) return;
    const float* hr = nod_s[r];
    float va = 0.f, wa = 0.f;
#pragma unroll 4
    for (int k = 0; k < H_; ++k) {
        const float hk = hr[k];
        va = fmaf(hk, Wv[k * H_ + j], va);
        wa = fmaf(hk, Ww[k * H_ + j], wa);
    }
    hv[(size_t)(row0 + r) * H_ + j] = va;
    hw[(size_t)(row0 + r) * H_ + j] = wa;
}

// ---------------------------------------------------------------------------
// K2: one fused message pass. 2 rows per 256-thread block (r = t>>7, j = t&127,
// lane j = h). Message loop: coalesced global hw reads (L1/L2-hot), LDS
// broadcast edges+mask. Then tanh update and (optionally) next pass's hv/hw.
// hv is row-local (in-place); hw double-buffered (read by other blocks).
__global__ __launch_bounds__(256, 6) void k_pass(const float* __restrict__ edges,
                                                 const float* __restrict__ We,
                                                 const float* __restrict__ Wu,
                                                 const float* __restrict__ Wv,
                                                 const float* __restrict__ Ww,
                                                 const float* __restrict__ nmask,
                                                 float* __restrict__ hv_io,
                                                 const float* __restrict__ hw_in,
                                                 float* __restrict__ hw_out,
                                                 const float* __restrict__ hid_in,
                                                 float* __restrict__ hidden,
                                                 int do_proj) {
    __shared__ float4 e_s[2][N_];      // 4 KB
    __shared__ float  m_s[2][N_];      // 1 KB
    __shared__ float  hid_s[2][H_];    // 800 B
    __shared__ float  msg_s[2][H_];    // 800 B
    __shared__ float  hn_s[2][H_];     // 800 B

    const int row0 = blockIdx.x * 2;
    const int b = row0 >> 7;
    const int t = threadIdx.x, r = t >> 7, j = t & 127;
    const int row = row0 + r;

    {   // stage both rows' edges (one float4 per thread, coalesced 4 KB) + mask
        const float4* eg = (const float4*)(edges + (size_t)row0 * N_ * 4);
        const float4 e = eg[t];                   // t == r*128 + j
        e_s[r][j] = e;
        const float s = (e.x + e.y) + (e.z + e.w);
        m_s[r][j] = (s != 0.f) ? 1.f : 0.f;
    }
    {   // stage pre-update hidden rows (50 float4)
        const float4* hg = (const float4*)(hid_in + (size_t)row0 * H_);
        if (t < 50) ((float4*)hid_s)[t] = hg[t];
    }
    __syncthreads();

    const bool act = (j < H_);
    if (act) {
        const float hvv = hv_io[(size_t)row * H_ + j];
        const float we0 = We[0 * H_ + j], we1 = We[1 * H_ + j];
        const float we2 = We[2 * H_ + j], we3 = We[3 * H_ + j];
        const float* hwp = hw_in + (size_t)b * N_ * H_ + j;
        float acc = 0.f;
#pragma unroll 8
        for (int w = 0; w < N_; ++w) {
            const float  hww = hwp[w * H_];       // coalesced 400B over lanes
            const float4 e = e_s[r][w];           // LDS broadcast
            const float  m = m_s[r][w];           // LDS broadcast
            float p = hvv + hww;
            p = fmaf(e.x, we0, p);
            p = fmaf(e.y, we1, p);
            p = fmaf(e.z, we2, p);
            p = fmaf(e.w, we3, p);
            acc = fmaf(m, fmaxf(p, 0.f), acc);
        }
        msg_s[r][j] = acc;
    }
    __syncthreads();

    float nh = 0.f;
    if (act) {
        const float* hr = hid_s[r];
        const float* mr = msg_s[r];
        float u = 0.f;
#pragma unroll 8
        for (int k = 0; k < H_; ++k)
            u = fmaf(hr[k], Wu[k * H_ + j], u);
#pragma unroll 8
        for (int k = 0; k < H_; ++k)
            u = fmaf(mr[k], Wu[(H_ + k) * H_ + j], u);
        const float nm = nmask[row];
        nh = (nm != 0.f) ? tanhf(u) : hr[j];
        hidden[(size_t)row * H_ + j] = nh;
        if (do_proj) hn_s[r][j] = nh;
    }

    if (do_proj) {
        __syncthreads();
        if (act) {
            const float* hr = hn_s[r];
            float va = 0.f, wa = 0.f;
#pragma unroll 4
            for (int k = 0; k < H_; ++k) {
                const float hk = hr[k];
                va = fmaf(hk, Wv[k * H_ + j], va);
                wa = fmaf(hk, Ww[k * H_ + j], wa);
            }
            hv_io[(size_t)row * H_ + j] = va;     // row-local: safe in-place
            hw_out[(size_t)row * H_ + j] = wa;    // double-buffered
        }
    }
}

// ---------------------------------------------------------------------------
// K3: readout. 2 rows/block; relu([hid,nodes]@Wr), masked, block-reduce, atomic.
__global__ __launch_bounds__(256, 6) void k_readout(const float* __restrict__ hidden,
                                                    const float* __restrict__ nodes,
                                                    const float* __restrict__ Wr,
                                                    const float* __restrict__ nmask,
                                                    float* __restrict__ out) {
    __shared__ float hid_s[2][H_], nod_s[2][H_], red_s[2][H_];
    const int row0 = blockIdx.x * 2, b = row0 >> 7;
    const int t = threadIdx.x, r = t >> 7, j = t & 127;
    const int row = row0 + r;
    {
        const float4* hg = (const float4*)(hidden + (size_t)row0 * H_);
        const float4* ng = (const float4*)(nodes + (size_t)row0 * H_);
        if (t < 50) {
            ((float4*)hid_s)[t] = hg[t];
            ((float4*)nod_s)[t] = ng[t];
        }
    }
    __syncthreads();
    if (j < H_) {
        const float* hr = hid_s[r];
        const float* nr = nod_s[r];
        float u = 0.f;
#pragma unroll 8
        for (int k = 0; k < H_; ++k)
            u = fmaf(hr[k], Wr[k * H_ + j], u);
#pragma unroll 8
        for (int k = 0; k < H_; ++k)
            u = fmaf(nr[k], Wr[(H_ + k) * H_ + j], u);
        red_s[r][j] = nmask[row] * fmaxf(u, 0.f);
    }
    __syncthreads();
    if (t < H_) atomicAdd(out + b * H_ + t, red_s[0][t] + red_s[1][t]);
}

// ---------------------------------------------------------------------------
extern "C" void kernel_launch(void* const* d_in, const int* in_sizes, int n_in,
                              void* d_out, int out_size, void* d_ws, size_t ws_size,
                              hipStream_t stream) {
    const float* nodes = (const float*)d_in[0];
    const float* edges = (const float*)d_in[1];
    const float* Wv    = (const float*)d_in[2];
    const float* Ww    = (const float*)d_in[3];
    const float* We    = (const float*)d_in[4];
    const float* Wu    = (const float*)d_in[5];
    const float* Wr    = (const float*)d_in[6];
    float* out = (float*)d_out;

    float* hidden = (float*)d_ws;     // RH
    float* hv     = hidden + RH;      // RH
    float* hwA    = hv + RH;          // RH
    float* hwB    = hwA + RH;         // RH
    float* nmask  = hwB + RH;         // ROWS

    hipMemsetAsync(d_out, 0, (size_t)out_size * sizeof(float), stream);

    k_mask<<<ROWS / 4, 256, 0, stream>>>(edges, nmask);
    k_proj0<<<ROWS / 2, 256, 0, stream>>>(nodes, Wv, Ww, hv, hwA);

    k_pass<<<ROWS / 2, 256, 0, stream>>>(edges, We, Wu, Wv, Ww, nmask,
                                         hv, hwA, hwB, nodes, hidden, 1);
    k_pass<<<ROWS / 2, 256, 0, stream>>>(edges, We, Wu, Wv, Ww, nmask,
                                         hv, hwB, hwA, hidden, hidden, 1);
    k_pass<<<ROWS / 2, 256, 0, stream>>>(edges, We, Wu, Wv, Ww, nmask,
                                         hv, hwA, hwB, hidden, hidden, 0);

    k_readout<<<ROWS / 2, 256, 0, stream>>>(hidden, nodes, Wr, nmask, out);
}